// Round 9
// baseline (2526.500 us; speedup 1.0000x reference)
//
#include <hip/hip_runtime.h>

#define Hd 128
#define HF 64
#define Tn 1024
#define Dn 5
#define Ln 16
#define Bn 512
// gap-padded hidden layout: h[0..63] at [0..63], h[64..127] at [68..131].
// The +4-float gap puts the two per-wave broadcast addresses (even lanes kk=0,
// odd lanes kk=1) on DISJOINT bank quads -> kills the 2.7e8 conflict cycles
// measured in round 4 (both halves previously aliased banks {4k..4k+3}).
#define HP 132
#define GJ(j) ((j) + (((j) >> 6) << 2))

__device__ __forceinline__ float sigm(float x) { return 1.0f / (1.0f + __expf(-x)); }
__device__ __forceinline__ float tanh_fast(float x) { return 1.0f - 2.0f / (1.0f + __expf(2.0f * x)); }

// Persistent GRU autoencoder, K-split-by-2 layout.
// grid = 256 WGs (1/CU), block = 512 threads (8 waves = 2 waves/SIMD).
// Thread (bl, j, kk): owns half kk of W_hh rows {j, 128+j, 256+j} = 192 VGPRs.
// amdgpu_waves_per_eu(2,2): round 4 showed the allocator targeting >2 waves/EU
// and capping arch VGPRs at 128 (weights pushed to AGPRs -> accvgpr moves ~2x
// inner-loop VALU). Pinning min=max=2 lets it use the full 256 arch VGPRs.
__global__ __launch_bounds__(512)
__attribute__((amdgpu_waves_per_eu(2, 2)))
void gru_ae_kernel(
    const float* __restrict__ x,
    const float* __restrict__ eWih, const float* __restrict__ eWhh,
    const float* __restrict__ ebih, const float* __restrict__ ebhh,
    const float* __restrict__ efcW, const float* __restrict__ efcb,
    const float* __restrict__ dfcW, const float* __restrict__ dfcb,
    const float* __restrict__ dWih, const float* __restrict__ dWhh,
    const float* __restrict__ dbih, const float* __restrict__ dbhh,
    const float* __restrict__ oW, const float* __restrict__ ob,
    float* __restrict__ out)
{
    __shared__ __align__(16) float henc[2][2][HP];   // ping-pong encoder h per row (gapped)
    __shared__ __align__(16) float hs[2][32][HP];    // decoder 32-step h history (gapped)
    __shared__ __align__(16) float hdi[2][HP];       // decoder input-hidden (gapped)
    __shared__ float zl[2][Ln];                      // latent z

    const int tid  = threadIdx.x;
    const int bl   = tid >> 8;       // local batch row 0/1
    const int loc  = tid & 255;
    const int j    = loc >> 1;       // hidden index 0..127
    const int kk   = loc & 1;        // K-half 0/1
    const int b    = blockIdx.x * 2 + bl;
    const int koff = kk * HF;        // global-memory K offset (ungapped)
    const int klds = kk * 68;        // LDS K offset (gapped)

    // ---- encoder W_hh half-rows into registers (192 VGPRs) ----
    float4 wr[16], wz[16], wn[16];
    {
        const float4* p0 = (const float4*)(eWhh + (size_t)j * Hd + koff);
        const float4* p1 = (const float4*)(eWhh + (size_t)(Hd + j) * Hd + koff);
        const float4* p2 = (const float4*)(eWhh + (size_t)(2 * Hd + j) * Hd + koff);
#pragma unroll
        for (int k = 0; k < 16; ++k) { wr[k] = p0[k]; wz[k] = p1[k]; wn[k] = p2[k]; }
    }
    // input-projection rows (D=5) + biases (r/z biases folded: bih+bhh)
    float wir[5], wiz[5], win[5];
#pragma unroll
    for (int d = 0; d < 5; ++d) {
        wir[d] = eWih[(size_t)j * Dn + d];
        wiz[d] = eWih[(size_t)(Hd + j) * Dn + d];
        win[d] = eWih[(size_t)(2 * Hd + j) * Dn + d];
    }
    float bR = ebih[j] + ebhh[j];
    float bZ = ebih[Hd + j] + ebhh[Hd + j];
    float bihn = ebih[2 * Hd + j];
    float bhhn = ebhh[2 * Hd + j];

    if (loc < Hd) { henc[0][bl][GJ(loc)] = 0.f; henc[1][bl][GJ(loc)] = 0.f; }
    __syncthreads();

    float h_self = 0.f;
    int p = 0;
    const float* xrow = x + (size_t)b * Tn * Dn;
    // x prefetch, distance 2 (covers ~900-cycle HBM miss; step body ~450 cyc)
    float xa0 = xrow[0], xa1 = xrow[1], xa2 = xrow[2], xa3 = xrow[3], xa4 = xrow[4];
    const float* xq1 = xrow + Dn;
    float xb0 = xq1[0], xb1 = xq1[1], xb2 = xq1[2], xb3 = xq1[3], xb4 = xq1[4];

    // ================= encoder: 1024 steps, 1 barrier/step =================
#pragma unroll 1
    for (int t = 0; t < Tn; ++t) {
        const int tn = (t + 2 < Tn) ? (t + 2) : (Tn - 1);
        const float* xq = xrow + tn * Dn;
        float nx0 = xq[0], nx1 = xq[1], nx2 = xq[2], nx3 = xq[3], nx4 = xq[4];

        float xpr = wir[0]*xa0 + wir[1]*xa1 + wir[2]*xa2 + wir[3]*xa3 + wir[4]*xa4;
        float xpz = wiz[0]*xa0 + wiz[1]*xa1 + wiz[2]*xa2 + wiz[3]*xa3 + wiz[4]*xa4;
        float xpn = win[0]*xa0 + win[1]*xa1 + win[2]*xa2 + win[3]*xa3 + win[4]*xa4;

        const float4* hv = (const float4*)&henc[p][bl][klds];
        float ar = 0.f, az = 0.f, an = 0.f;
#pragma unroll
        for (int k = 0; k < 16; ++k) {
            float4 h4 = hv[k];
            ar = fmaf(wr[k].x, h4.x, ar); az = fmaf(wz[k].x, h4.x, az); an = fmaf(wn[k].x, h4.x, an);
            ar = fmaf(wr[k].y, h4.y, ar); az = fmaf(wz[k].y, h4.y, az); an = fmaf(wn[k].y, h4.y, an);
            ar = fmaf(wr[k].z, h4.z, ar); az = fmaf(wz[k].z, h4.z, az); an = fmaf(wn[k].z, h4.z, an);
            ar = fmaf(wr[k].w, h4.w, ar); az = fmaf(wz[k].w, h4.w, az); an = fmaf(wn[k].w, h4.w, an);
        }
        ar += __shfl_xor(ar, 1); az += __shfl_xor(az, 1); an += __shfl_xor(an, 1);
        float r  = sigm(xpr + ar + bR);
        float zg = sigm(xpz + az + bZ);
        float n  = tanh_fast(xpn + bihn + r * (an + bhhn));
        float hnew = fmaf(zg, h_self - n, n);   // (1-z)*n + z*h
        h_self = hnew;
        if (!kk) henc[p ^ 1][bl][GJ(j)] = hnew;
        xa0 = xb0; xa1 = xb1; xa2 = xb2; xa3 = xb3; xa4 = xb4;
        xb0 = nx0; xb1 = nx1; xb2 = nx2; xb3 = nx3; xb4 = nx4;
        __syncthreads();
        p ^= 1;
    }

    // ================= latent z =================
    if (loc < Ln) {
        const float4* wp = (const float4*)(efcW + (size_t)loc * Hd);
        float acc = efcb[loc];
#pragma unroll
        for (int k = 0; k < 32; ++k) {
            float4 w4 = wp[k];
            float4 h4 = *(const float4*)&henc[p][bl][4 * k + ((k >> 4) << 2)];
            acc = fmaf(w4.x, h4.x, fmaf(w4.y, h4.y, fmaf(w4.z, h4.z, fmaf(w4.w, h4.w, acc))));
        }
        out[(size_t)Bn * Tn * Dn + (size_t)b * Ln + loc] = acc;
        zl[bl][loc] = acc;
    }
    __syncthreads();

    // ================= h_dec_in = z @ dec_fc_W.T + dec_fc_b =================
    if (loc < Hd) {
        const float4* wp = (const float4*)(dfcW + (size_t)loc * Ln);
        float acc = dfcb[loc];
#pragma unroll
        for (int l = 0; l < 4; ++l) {
            float4 w4 = wp[l];
            acc = fmaf(w4.x, zl[bl][4*l+0], acc);
            acc = fmaf(w4.y, zl[bl][4*l+1], acc);
            acc = fmaf(w4.z, zl[bl][4*l+2], acc);
            acc = fmaf(w4.w, zl[bl][4*l+3], acc);
        }
        hdi[bl][GJ(loc)] = acc;
    }
    __syncthreads();

    // ================= xp_dec (constant over decoder steps) =================
    float xdr, xdz, xdn;
    {
        const float4* p0 = (const float4*)(dWih + (size_t)j * Hd + koff);
        const float4* p1 = (const float4*)(dWih + (size_t)(Hd + j) * Hd + koff);
        const float4* p2 = (const float4*)(dWih + (size_t)(2 * Hd + j) * Hd + koff);
#pragma unroll
        for (int k = 0; k < 16; ++k) { wr[k] = p0[k]; wz[k] = p1[k]; wn[k] = p2[k]; }
        const float4* hv = (const float4*)&hdi[bl][klds];
        float a0 = 0.f, a1 = 0.f, a2 = 0.f;
#pragma unroll
        for (int k = 0; k < 16; ++k) {
            float4 h4 = hv[k];
            a0 = fmaf(wr[k].x, h4.x, a0); a1 = fmaf(wz[k].x, h4.x, a1); a2 = fmaf(wn[k].x, h4.x, a2);
            a0 = fmaf(wr[k].y, h4.y, a0); a1 = fmaf(wz[k].y, h4.y, a1); a2 = fmaf(wn[k].y, h4.y, a2);
            a0 = fmaf(wr[k].z, h4.z, a0); a1 = fmaf(wz[k].z, h4.z, a1); a2 = fmaf(wn[k].z, h4.z, a2);
            a0 = fmaf(wr[k].w, h4.w, a0); a1 = fmaf(wz[k].w, h4.w, a1); a2 = fmaf(wn[k].w, h4.w, a2);
        }
        a0 += __shfl_xor(a0, 1); a1 += __shfl_xor(a1, 1); a2 += __shfl_xor(a2, 1);
        xdr = a0 + dbih[j];
        xdz = a1 + dbih[Hd + j];
        xdn = a2 + dbih[2 * Hd + j];
    }

    // ---- decoder W_hh half-rows ----
    {
        const float4* p0 = (const float4*)(dWhh + (size_t)j * Hd + koff);
        const float4* p1 = (const float4*)(dWhh + (size_t)(Hd + j) * Hd + koff);
        const float4* p2 = (const float4*)(dWhh + (size_t)(2 * Hd + j) * Hd + koff);
#pragma unroll
        for (int k = 0; k < 16; ++k) { wr[k] = p0[k]; wz[k] = p1[k]; wn[k] = p2[k]; }
    }
    bR = dbhh[j];
    bZ = dbhh[Hd + j];
    bhhn = dbhh[2 * Hd + j];

    if (loc < Hd) hs[bl][31][GJ(loc)] = 0.f;   // "previous h" for decoder step 0
    h_self = 0.f;
    __syncthreads();

    // ================= decoder: 1024 steps in 32-step tiles =================
#pragma unroll 1
    for (int s0 = 0; s0 < Tn; s0 += 32) {
#pragma unroll 1
        for (int ss = 0; ss < 32; ++ss) {
            const int ip = (ss + 31) & 31;
            const float4* hv = (const float4*)&hs[bl][ip][klds];
            float ar = 0.f, az = 0.f, an = 0.f;
#pragma unroll
            for (int k = 0; k < 16; ++k) {
                float4 h4 = hv[k];
                ar = fmaf(wr[k].x, h4.x, ar); az = fmaf(wz[k].x, h4.x, az); an = fmaf(wn[k].x, h4.x, an);
                ar = fmaf(wr[k].y, h4.y, ar); az = fmaf(wz[k].y, h4.y, az); an = fmaf(wn[k].y, h4.y, an);
                ar = fmaf(wr[k].z, h4.z, ar); az = fmaf(wz[k].z, h4.z, az); an = fmaf(wn[k].z, h4.z, an);
                ar = fmaf(wr[k].w, h4.w, ar); az = fmaf(wz[k].w, h4.w, az); an = fmaf(wn[k].w, h4.w, an);
            }
            ar += __shfl_xor(ar, 1); az += __shfl_xor(az, 1); an += __shfl_xor(an, 1);
            float r  = sigm(xdr + ar + bR);
            float zg = sigm(xdz + az + bZ);
            float n  = tanh_fast(xdn + r * (an + bhhn));
            float hnew = fmaf(zg, h_self - n, n);
            h_self = hnew;
            if (!kk) hs[bl][ss][GJ(j)] = hnew;
            __syncthreads();
        }

        // ---- bulk recon projection for steps s0..s0+31 (coalesced stores) ----
        if (tid < 320) {
            const int rowp = tid / 160, o = tid % 160;
            const int i = o / 5, d = o % 5;
            const float4* wrow = (const float4*)(oW + (size_t)d * Hd);
            float ac0 = ob[d], ac1 = 0.f;
#pragma unroll
            for (int q = 0; q < 32; q += 2) {
                const int qa = (q + i) & 31, qb = (q + 1 + i) & 31;
                float4 ha = *(const float4*)&hs[rowp][i][4 * qa + ((qa >> 4) << 2)];
                float4 wa = wrow[qa];
                float4 hb = *(const float4*)&hs[rowp][i][4 * qb + ((qb >> 4) << 2)];
                float4 wb = wrow[qb];
                ac0 = fmaf(wa.x, ha.x, fmaf(wa.y, ha.y, fmaf(wa.z, ha.z, fmaf(wa.w, ha.w, ac0))));
                ac1 = fmaf(wb.x, hb.x, fmaf(wb.y, hb.y, fmaf(wb.z, hb.z, fmaf(wb.w, hb.w, ac1))));
            }
            out[((size_t)(blockIdx.x * 2 + rowp) * Tn + s0 + i) * Dn + d] = ac0 + ac1;
        }
        __syncthreads();   // protect hs before next tile overwrites slots
    }
}

extern "C" void kernel_launch(void* const* d_in, const int* in_sizes, int n_in,
                              void* d_out, int out_size, void* d_ws, size_t ws_size,
                              hipStream_t stream) {
    const float* x    = (const float*)d_in[0];
    const float* eWih = (const float*)d_in[1];
    const float* eWhh = (const float*)d_in[2];
    const float* ebih = (const float*)d_in[3];
    const float* ebhh = (const float*)d_in[4];
    const float* efcW = (const float*)d_in[5];
    const float* efcb = (const float*)d_in[6];
    const float* dfcW = (const float*)d_in[7];
    const float* dfcb = (const float*)d_in[8];
    const float* dWih = (const float*)d_in[9];
    const float* dWhh = (const float*)d_in[10];
    const float* dbih = (const float*)d_in[11];
    const float* dbhh = (const float*)d_in[12];
    const float* oW   = (const float*)d_in[13];
    const float* ob   = (const float*)d_in[14];
    float* out = (float*)d_out;

    gru_ae_kernel<<<dim3(Bn / 2), dim3(512), 0, stream>>>(
        x, eWih, eWhh, ebih, ebhh, efcW, efcb, dfcW, dfcb,
        dWih, dWhh, dbih, dbhh, oW, ob, out);
}